// Round 11
// baseline (60.887 us; speedup 1.0000x reference)
//
#include <hip/hip_runtime.h>
#include <hip/hip_bf16.h>
#include <math.h>

#define M 50
#define SQRT5 2.2360679774997896f

typedef short  bf16x8 __attribute__((ext_vector_type(8)));
typedef float  f32x4v __attribute__((ext_vector_type(4)));

__constant__ float c_zscale[5] = {0.25f, 0.2f, 0.08f, 400.0f, 10.0f};
__constant__ float c_zshift[5] = {0.0f, 0.0f, 0.0f, 800.0f, 12.0f};

#if __has_builtin(__builtin_amdgcn_sqrtf)
__device__ __forceinline__ float fsqrt(float x) { return __builtin_amdgcn_sqrtf(x); }
#else
__device__ __forceinline__ float fsqrt(float x) { return sqrtf(x); }
#endif

#if __has_builtin(__builtin_amdgcn_exp2f)
__device__ __forceinline__ float fexp2(float x) { return __builtin_amdgcn_exp2f(x); }
#else
__device__ __forceinline__ float fexp2(float x) { return exp2f(x); }
#endif

#if __has_builtin(__builtin_amdgcn_rcpf)
__device__ __forceinline__ float frcp(float x) { return __builtin_amdgcn_rcpf(x); }
#else
__device__ __forceinline__ float frcp(float x) { return 1.0f / x; }
#endif

__device__ __forceinline__ float lane_bcast(float v, int lane) {
    return __builtin_bit_cast(float,
        __builtin_amdgcn_readlane(__builtin_bit_cast(int, v), lane));
}

__device__ __forceinline__ unsigned short bfu(float f) {
    return __builtin_bit_cast(unsigned short, __float2bfloat16(f));
}

// ---- preprocessor 0..49 repeat machinery (literal unrolling is mandatory:
//      #pragma unroll silently failed on 50-deep pivot loops in rounds 6/7 ->
//      runtime indices -> scratch lowering) ----
#define FOR50(F) F(0) F(1) F(2) F(3) F(4) F(5) F(6) F(7) F(8) F(9) \
  F(10) F(11) F(12) F(13) F(14) F(15) F(16) F(17) F(18) F(19) \
  F(20) F(21) F(22) F(23) F(24) F(25) F(26) F(27) F(28) F(29) \
  F(30) F(31) F(32) F(33) F(34) F(35) F(36) F(37) F(38) F(39) \
  F(40) F(41) F(42) F(43) F(44) F(45) F(46) F(47) F(48) F(49)
#define FOR50P(F, p) F(0,p) F(1,p) F(2,p) F(3,p) F(4,p) F(5,p) F(6,p) F(7,p) F(8,p) F(9,p) \
  F(10,p) F(11,p) F(12,p) F(13,p) F(14,p) F(15,p) F(16,p) F(17,p) F(18,p) F(19,p) \
  F(20,p) F(21,p) F(22,p) F(23,p) F(24,p) F(25,p) F(26,p) F(27,p) F(28,p) F(29,p) \
  F(30,p) F(31,p) F(32,p) F(33,p) F(34,p) F(35,p) F(36,p) F(37,p) F(38,p) F(39,p) \
  F(40,p) F(41,p) F(42,p) F(43,p) F(44,p) F(45,p) F(46,p) F(47,p) F(48,p) F(49,p)

// ---- Phase A: Cholesky of K' = K + 1e-4 I (lane i owns ROW i in registers)
#define DECL_C(i) float c##i;
#define INIT_C(i) c##i = s_K[lrow * M + (i)];
#define CH_UPD(i, p) if ((i) > (p)) { \
    const float cj = lane_bcast(c##p, (i)); \
    c##i = fmaf(-c##p, cj, c##i); }
#define CH_PIVOT(p) { \
    const float dp  = lane_bcast(c##p, (p)); \
    const float inv = frcp(fsqrt(dp)); \
    c##p *= inv; \
    if (lane < M) s_K[lane * M + (p)] = c##p; \
    FOR50P(CH_UPD, p) }

// ---- Phase B: lane j solves L y = e_j (forward substitution; lane-local)
#define DECL_Y(i) float y##i;
#define TSU(q, i) if ((q) < (i)) acc = fmaf(-s_K[(i) * M + (q)], y##q, acc);
#define TS_ROW(i) { \
    float acc = (lane == (i)) ? 1.0f : 0.0f; \
    FOR50P(TSU, i) \
    y##i = acc * frcp(s_K[(i) * M + (i)]); }

// ---- Emission: Wt[n][lane] = bf16(pv * Linv[n][lane]), row-major [64][64]
#define W_EMIT(i) wtp[(i) * 64 + lane] = bfu(pv * y##i);

// ---------------------------------------------------------------------------
// ws layout (floats):
//   [0   .. 250)   Zb[m][j] = -2*sqrt5*Zs[m][j]
//   [256 .. 306)   z2s[m]   = |sqrt5*Zs[m]|^2 + 5e-8
//   [320 .. 325)   ils[j]   = sqrt5 * inv_ls[j]
//   [326]          prior_var
//   [512 .. 2560)  Wt: bf16[64][64], Wt[n][m] = pv*Linv[n][m], zero-padded
// ---------------------------------------------------------------------------
__global__ __launch_bounds__(256, 1) void gp_setup(const float* __restrict__ log_ls,
                                                   const float* __restrict__ log_var,
                                                   const float* __restrict__ zraw,
                                                   float* __restrict__ ws) {
    __shared__ float s_ils[5];
    __shared__ float s_pv;
    __shared__ float s_Zs[M * 5];
    __shared__ float s_K[M * M];

    const int t = threadIdx.x;
    unsigned short* wtp = (unsigned short*)(ws + 512);

    if (t == 0) s_pv = expf(log_var[0]);
    if (t < 5)  s_ils[t] = 1.0f / (expf(log_ls[t]) + 1e-8f);
    __syncthreads();
    if (t < M * 5) {
        int j = t % 5;
        s_Zs[t] = (tanhf(zraw[t]) * c_zscale[j] + c_zshift[j]) * s_ils[j];
    }
    __syncthreads();
    const float pv = s_pv;

    // Zero Wt region + build K + 1e-4 I (parallel across 256 threads)
    for (int e = t; e < 4096; e += 256) wtp[e] = 0;
    for (int e = t; e < M * M; e += 256) {
        int i = e / M, jj = e % M;
        float d2 = 0.0f;
        #pragma unroll
        for (int q = 0; q < 5; ++q) {
            float df = s_Zs[i * 5 + q] - s_Zs[jj * 5 + q];
            d2 = fmaf(df, df, d2);
        }
        float d = fsqrt(d2 + 1e-8f);
        float s = SQRT5 * d;
        s_K[e] = pv * (1.0f + s + (5.0f / 3.0f) * (d * d)) * expf(-s)
                 + ((i == jj) ? 1e-4f : 0.0f);
    }
    __syncthreads();

    // Wave 0: Cholesky K' = L L^T (registers, flush L to s_K), then
    // lane-local trisolve Linv columns, then bf16 Wt emission.
    if (t < 64) {
        const int lane = t;
        const int lrow = (t < M) ? t : (M - 1);
        {
            FOR50(DECL_C)
            FOR50(INIT_C)
            FOR50(CH_PIVOT)
        }
        {
            FOR50(DECL_Y)
            FOR50(TS_ROW)
            FOR50(W_EMIT)
        }
    }

    // Independent emissions (all threads; disjoint regions)
    if (t < M * 5) ws[t] = -2.0f * SQRT5 * s_Zs[t];
    if (t < M) {
        float z2 = 0.0f;
        #pragma unroll
        for (int q = 0; q < 5; ++q) {
            float v = SQRT5 * s_Zs[t * 5 + q];
            z2 = fmaf(v, v, z2);
        }
        ws[256 + t] = z2 + 5e-8f;
    }
    if (t < 5)  ws[320 + t] = SQRT5 * s_ils[t];
    if (t == 0) ws[326] = pv;
}

// ---------------------------------------------------------------------------
// Main kernel. Round-11 change: k-gen, bf16-pack, and LDS store are FUSED
// per 8-value chunk -> no k[50] array exists (round-10 pathology: 2100 VALU
// instr/wave vs ~900 in source because k[50]'s long live range was parked in
// AGPRs / rematerialized behind VGPR_Count=64). Max live k-state: 2 floats
// + 4 packed words. Per-chunk asm memory fence stops the scheduler from
// re-hoisting all chunks into one long live range.
// ---------------------------------------------------------------------------
__device__ __forceinline__ float kval(const float* __restrict__ Zb,
                                      const float* __restrict__ z2s,
                                      const float xs[5], float x2, int m) {
    float u = x2 + z2s[m];
    #pragma unroll
    for (int j = 0; j < 5; ++j) u = fmaf(Zb[m * 5 + j], xs[j], u);
    u = fmaxf(u, 5e-8f);
    float s = fsqrt(u);
    float e = fexp2(s * -1.4426950408889634f);          // exp(-s)
    return fmaf(u, (1.0f / 3.0f), 1.0f + s) * e;
}

__global__ __launch_bounds__(256) void gp_var(const float* __restrict__ x,
                                              const float* __restrict__ ws,
                                              float* __restrict__ out, int B) {
    __shared__ float sx[1280];
    __shared__ __align__(16) unsigned short sk[4 * 64 * 64];   // 32 KB
    const int t    = threadIdx.x;
    const int lane = t & 63;
    const int wid  = t >> 6;
    const long long base = (long long)blockIdx.x * 1280;

    {
        const long long tot = (long long)B * 5;
        const float4* xv = (const float4*)(x + base);
        for (int i = t; i < 320; i += 256) {
            if (base + (long long)i * 4 + 3 < tot) ((float4*)sx)[i] = xv[i];
        }
    }
    __syncthreads();

    const float* __restrict__ Zb  = ws;
    const float* __restrict__ z2s = ws + 256;
    const float* __restrict__ ils = ws + 320;
    const float pv = ws[326];

    float xs[5];
    #pragma unroll
    for (int j = 0; j < 5; ++j) xs[j] = sx[t * 5 + j] * ils[j];

    float x2 = 0.0f;
    #pragma unroll
    for (int j = 0; j < 5; ++j) x2 = fmaf(xs[j], xs[j], x2);

    // Fused k-gen -> bf16 pack -> swizzled LDS store, one 8-kdim chunk at a
    // time (chunks 6 upper half / 7 are zero padding: kdims 50..63).
    char* kbase = (char*)sk + wid * 8192;
    const int swz_w = (lane & 7) << 4;
    #pragma unroll
    for (int c = 0; c < 8; ++c) {
        unsigned int w0 = 0, w1 = 0, w2 = 0, w3 = 0;
        if (c < 6) {
            float a, b;
            a = kval(Zb, z2s, xs, x2, c * 8 + 0);
            b = kval(Zb, z2s, xs, x2, c * 8 + 1);
            w0 = (unsigned int)bfu(a) | ((unsigned int)bfu(b) << 16);
            a = kval(Zb, z2s, xs, x2, c * 8 + 2);
            b = kval(Zb, z2s, xs, x2, c * 8 + 3);
            w1 = (unsigned int)bfu(a) | ((unsigned int)bfu(b) << 16);
            a = kval(Zb, z2s, xs, x2, c * 8 + 4);
            b = kval(Zb, z2s, xs, x2, c * 8 + 5);
            w2 = (unsigned int)bfu(a) | ((unsigned int)bfu(b) << 16);
            a = kval(Zb, z2s, xs, x2, c * 8 + 6);
            b = kval(Zb, z2s, xs, x2, c * 8 + 7);
            w3 = (unsigned int)bfu(a) | ((unsigned int)bfu(b) << 16);
        } else if (c == 6) {
            float a, b;
            a = kval(Zb, z2s, xs, x2, 48);
            b = kval(Zb, z2s, xs, x2, 49);
            w0 = (unsigned int)bfu(a) | ((unsigned int)bfu(b) << 16);
        }
        int off = lane * 128 + ((c * 16) ^ swz_w);
        *(int4*)(kbase + off) = make_int4((int)w0, (int)w1, (int)w2, (int)w3);
        asm volatile("" ::: "memory");   // fence: keep chunks' live ranges apart
    }

    // W fragments from global (L2-resident)
    const int r15 = lane & 15, g = lane >> 4;
    bf16x8 wf[4][2];
    const char* wtb = (const char*)(ws + 512);
    #pragma unroll
    for (int tc = 0; tc < 4; ++tc) {
        #pragma unroll
        for (int ks = 0; ks < 2; ++ks) {
            int o = ((tc * 16 + r15) * 64 + ks * 32 + g * 8) * 2;
            wf[tc][ks] = *(const bf16x8*)(wtb + o);
        }
    }

    // MFMA + per-reg square accumulation
    float part[4][4];
    #pragma unroll
    for (int tr = 0; tr < 4; ++tr) {
        const int r = tr * 16 + r15;
        const char* arow = kbase + r * 128;
        const int swz = (r15 & 7) << 4;
        bf16x8 a0 = *(const bf16x8*)(arow + ((g * 16) ^ swz));
        bf16x8 a1 = *(const bf16x8*)(arow + (((4 + g) * 16) ^ swz));
        #pragma unroll
        for (int tc = 0; tc < 4; ++tc) {
            f32x4v acc = {0.0f, 0.0f, 0.0f, 0.0f};
            acc = __builtin_amdgcn_mfma_f32_16x16x32_bf16(a0, wf[tc][0], acc, 0, 0, 0);
            acc = __builtin_amdgcn_mfma_f32_16x16x32_bf16(a1, wf[tc][1], acc, 0, 0, 0);
            #pragma unroll
            for (int rg = 0; rg < 4; ++rg) {
                part[tr][rg] = (tc == 0) ? acc[rg] * acc[rg]
                                         : fmaf(acc[rg], acc[rg], part[tr][rg]);
            }
        }
    }

    // butterfly-sum over the 16 lanes of each l>>4 group
    #pragma unroll
    for (int tr = 0; tr < 4; ++tr) {
        #pragma unroll
        for (int rg = 0; rg < 4; ++rg) {
            float v = part[tr][rg];
            v += __shfl_xor(v, 1);
            v += __shfl_xor(v, 2);
            v += __shfl_xor(v, 4);
            v += __shfl_xor(v, 8);
            part[tr][rg] = v;
        }
    }

    float red = part[0][0];
    #pragma unroll
    for (int i = 1; i < 16; ++i)
        if (r15 == i) red = part[i >> 2][i & 3];

    const int pt = blockIdx.x * 256 + wid * 64 + (r15 >> 2) * 16 + g * 4 + (r15 & 3);
    out[pt] = fsqrt(fmaxf(pv - red, 1e-6f));
}

extern "C" void kernel_launch(void* const* d_in, const int* in_sizes, int n_in,
                              void* d_out, int out_size, void* d_ws, size_t ws_size,
                              hipStream_t stream) {
    const float* x    = (const float*)d_in[0];
    const float* ll   = (const float*)d_in[1];
    const float* lv   = (const float*)d_in[2];
    const float* zraw = (const float*)d_in[3];
    float* out = (float*)d_out;
    float* ws  = (float*)d_ws;

    const int B = in_sizes[0] / 5;

    hipLaunchKernelGGL(gp_setup, dim3(1), dim3(256), 0, stream, ll, lv, zraw, ws);
    const int grid = (B + 255) / 256;
    hipLaunchKernelGGL(gp_var, dim3(grid), dim3(256), 0, stream, x, ws, out, B);
}